// Round 1
// baseline (31.915 us; speedup 1.0000x reference)
//
#include <hip/hip_runtime.h>

// MultiLevelEmbedding: out[b,t,:] = emb_tables[level_ids[b,t], token_ids[b,t], :]
//                                 + level_embed[level_ids[b,t], :]
// B=64, T=1024, L=4, VOCAB=258, D=512, fp32.
// Memory-bound: 128 MiB stream-out; gather sources are L2/L3-resident.

#define MLE_D     512
#define MLE_D4    128   // D / 4 (float4 elements per row)
#define MLE_VOCAB 258

__global__ __launch_bounds__(256) void MultiLevelEmbedding_34437047780006_kernel(
    const int* __restrict__ level_ids,
    const int* __restrict__ token_ids,
    const float* __restrict__ emb_tables,
    const float* __restrict__ level_embed,
    float* __restrict__ out,
    long long total_f4)   // n_rows * 128
{
    long long stride = (long long)gridDim.x * blockDim.x;
    for (long long i = (long long)blockIdx.x * blockDim.x + threadIdx.x;
         i < total_f4; i += stride) {
        int row = (int)(i >> 7);   // i / 128
        int d4  = (int)(i & 127);  // i % 128
        int lvl = level_ids[row];
        int tok = token_ids[row];
        const float4* tab = reinterpret_cast<const float4*>(
            emb_tables + ((long long)lvl * MLE_VOCAB + (long long)tok) * MLE_D);
        const float4* lev = reinterpret_cast<const float4*>(
            level_embed + (long long)lvl * MLE_D);
        float4 a = tab[d4];
        float4 b = lev[d4];
        float4 o;
        o.x = a.x + b.x;
        o.y = a.y + b.y;
        o.z = a.z + b.z;
        o.w = a.w + b.w;
        reinterpret_cast<float4*>(out)[i] = o;
    }
}

extern "C" void kernel_launch(void* const* d_in, const int* in_sizes, int n_in,
                              void* d_out, int out_size, void* d_ws, size_t ws_size,
                              hipStream_t stream) {
    const int*   level_ids   = (const int*)d_in[0];
    const int*   token_ids   = (const int*)d_in[1];
    const float* emb_tables  = (const float*)d_in[2];
    const float* level_embed = (const float*)d_in[3];
    float*       out         = (float*)d_out;

    int n_rows = in_sizes[0];                       // B*T = 65536
    long long total_f4 = (long long)n_rows * MLE_D4; // 8,388,608

    const int block = 256;
    long long want_blocks = (total_f4 + block - 1) / block;
    int grid = (int)(want_blocks < 2048 ? want_blocks : 2048);

    MultiLevelEmbedding_34437047780006_kernel<<<grid, block, 0, stream>>>(
        level_ids, token_ids, emb_tables, level_embed, out, total_f4);
}

// Round 3
// 27.409 us; speedup vs baseline: 1.1644x; 1.1644x over previous
//
#include <hip/hip_runtime.h>

// MultiLevelEmbedding: out[b,t,:] = emb_tables[level_ids[b,t], token_ids[b,t], :]
//                                 + level_embed[level_ids[b,t], :]
// B=64, T=1024, L=4, VOCAB=258, D=512, fp32.
// HBM-write-bound: 128 MiB out-stream; tables (2 MiB) are L2/L3-resident.
//
// Structure: one wave <-> one 2KiB row. Lane l covers float4 elements l and
// l+64 (two fully-coalesced 1KiB accesses per row). Row index is wave-uniform
// (readfirstlane-forced) so the id loads take the scalar path. 2-row unroll
// keeps two independent gather chains in flight. Nontemporal stores keep the
// write stream from evicting the tables out of per-XCD L2.
//
// NOTE: use clang ext_vector float4 (not HIP_vector_type) --
// __builtin_nontemporal_store only accepts scalar/vector-of-scalar pointees.

#define MLE_D     512
#define MLE_D4    128   // float4 per row
#define MLE_VOCAB 258

typedef float f32x4 __attribute__((ext_vector_type(4)));

__global__ __launch_bounds__(256) void MultiLevelEmbedding_34437047780006_kernel(
    const int* __restrict__ level_ids,
    const int* __restrict__ token_ids,
    const float* __restrict__ emb_tables,
    const float* __restrict__ level_embed,
    float* __restrict__ out,
    int nrows)
{
    const int lane = (int)(threadIdx.x & 63);
    const int wib  = __builtin_amdgcn_readfirstlane((int)(threadIdx.x >> 6)); // wave in block
    const int nw   = (int)gridDim.x * 4;            // total waves
    int gw = (int)blockIdx.x * 4 + wib;             // this wave's id (SGPR)

    const f32x4* __restrict__ levv = reinterpret_cast<const f32x4*>(level_embed);

    int row = gw;
    // 2 rows per iteration: two independent idx->table chains in flight.
    for (; row + nw < nrows; row += 2 * nw) {
        const int r0 = row;
        const int r1 = row + nw;
        const int lvl0 = __builtin_amdgcn_readfirstlane(level_ids[r0]);
        const int tok0 = __builtin_amdgcn_readfirstlane(token_ids[r0]);
        const int lvl1 = __builtin_amdgcn_readfirstlane(level_ids[r1]);
        const int tok1 = __builtin_amdgcn_readfirstlane(token_ids[r1]);

        const f32x4* __restrict__ t0 = reinterpret_cast<const f32x4*>(
            emb_tables + (long long)(lvl0 * MLE_VOCAB + tok0) * MLE_D);
        const f32x4* __restrict__ t1 = reinterpret_cast<const f32x4*>(
            emb_tables + (long long)(lvl1 * MLE_VOCAB + tok1) * MLE_D);

        f32x4 a0 = t0[lane];
        f32x4 b0 = t0[lane + 64];
        f32x4 a1 = t1[lane];
        f32x4 b1 = t1[lane + 64];

        f32x4 la0 = levv[lvl0 * MLE_D4 + lane];
        f32x4 lb0 = levv[lvl0 * MLE_D4 + lane + 64];
        f32x4 la1 = levv[lvl1 * MLE_D4 + lane];
        f32x4 lb1 = levv[lvl1 * MLE_D4 + lane + 64];

        f32x4* __restrict__ o0 = reinterpret_cast<f32x4*>(out + (long long)r0 * MLE_D);
        f32x4* __restrict__ o1 = reinterpret_cast<f32x4*>(out + (long long)r1 * MLE_D);

        __builtin_nontemporal_store(a0 + la0, o0 + lane);
        __builtin_nontemporal_store(b0 + lb0, o0 + lane + 64);
        __builtin_nontemporal_store(a1 + la1, o1 + lane);
        __builtin_nontemporal_store(b1 + lb1, o1 + lane + 64);
    }
    // tail (at most one row per wave)
    for (; row < nrows; row += nw) {
        const int lvl = __builtin_amdgcn_readfirstlane(level_ids[row]);
        const int tok = __builtin_amdgcn_readfirstlane(token_ids[row]);
        const f32x4* __restrict__ t = reinterpret_cast<const f32x4*>(
            emb_tables + (long long)(lvl * MLE_VOCAB + tok) * MLE_D);
        f32x4 a = t[lane];
        f32x4 b = t[lane + 64];
        f32x4 la = levv[lvl * MLE_D4 + lane];
        f32x4 lb = levv[lvl * MLE_D4 + lane + 64];
        f32x4* __restrict__ o = reinterpret_cast<f32x4*>(out + (long long)row * MLE_D);
        __builtin_nontemporal_store(a + la, o + lane);
        __builtin_nontemporal_store(b + lb, o + lane + 64);
    }
}

extern "C" void kernel_launch(void* const* d_in, const int* in_sizes, int n_in,
                              void* d_out, int out_size, void* d_ws, size_t ws_size,
                              hipStream_t stream) {
    const int*   level_ids   = (const int*)d_in[0];
    const int*   token_ids   = (const int*)d_in[1];
    const float* emb_tables  = (const float*)d_in[2];
    const float* level_embed = (const float*)d_in[3];
    float*       out         = (float*)d_out;

    const int nrows = in_sizes[0];   // B*T = 65536

    const int block = 256;           // 4 waves/block
    int grid = 2048;                 // 8192 waves -> 8 rows/wave
    int max_blocks = (nrows + 3) / 4;
    if (grid > max_blocks) grid = max_blocks;

    MultiLevelEmbedding_34437047780006_kernel<<<grid, block, 0, stream>>>(
        level_ids, token_ids, emb_tables, level_embed, out, nrows);
}